// Round 1
// baseline (1502.668 us; speedup 1.0000x reference)
//
#include <hip/hip_runtime.h>

#define N_NODES 100000
#define N_EDGES 1600000
#define D 64
#define BN_EPS 1e-5f

// ---------------------------------------------------------------------------
// K1: edge scatter-sum. 16 threads per edge, each handling a float4 chunk.
// neigh must be pre-zeroed (hipMemsetAsync in kernel_launch).
// ---------------------------------------------------------------------------
__global__ __launch_bounds__(256) void scatter_k(
    const float* __restrict__ feat, const int* __restrict__ src,
    const int* __restrict__ dst, float* __restrict__ neigh)
{
    long long t = (long long)blockIdx.x * 256 + threadIdx.x;
    int e = (int)(t >> 4);
    if (e >= N_EDGES) return;
    int c = ((int)t & 15) << 2;
    int s = src[e];
    int d = dst[e];
    float4 v = *(const float4*)(feat + (size_t)s * D + c);
    float* o = neigh + (size_t)d * D + c;
    unsafeAtomicAdd(o + 0, v.x);
    unsafeAtomicAdd(o + 1, v.y);
    unsafeAtomicAdd(o + 2, v.z);
    unsafeAtomicAdd(o + 3, v.w);
}

// ---------------------------------------------------------------------------
// K2: per 64-node tile: x = (1+eps)*feat + neigh; h2 = relu(x@W1+b1)@W2+b2.
// Writes h2 to h2out (d_out used as temp), accumulates BN partial sums into
// stats8 (8 shards of [sum[64], sumsq[64]]).
// Block = 256 threads; thread (m = t&15, g = t>>4) owns nodes n0=4m..4m+3,
// outputs j0=4g..4g+3 (4x4 register tile).
// LDS: W1s/W2s stride 68 (float4 reads, conflict-light); xs stride 65
// (scalar reads, 2 addrs/bank = free per m136).
// ---------------------------------------------------------------------------
__global__ __launch_bounds__(256) void mlp_k(
    const float* __restrict__ feat, const float* __restrict__ neigh,
    const float* __restrict__ epsp,
    const float* __restrict__ W1, const float* __restrict__ b1,
    const float* __restrict__ W2, const float* __restrict__ b2,
    float* __restrict__ h2out, float* __restrict__ stats8)
{
    __shared__ float W1s[64 * 68];
    __shared__ float W2s[64 * 68];
    __shared__ float xs[64 * 65];
    __shared__ float b1s[64], b2s[64];

    const int t  = threadIdx.x;
    const int nb = blockIdx.x * 64;

    // stage weights: 64x64 each, 1024 float4 per matrix / 256 threads
    #pragma unroll
    for (int i = 0; i < 4; ++i) {
        int l  = t + i * 256;          // float4 index 0..1023
        int k  = l >> 4;
        int j4 = (l & 15) << 2;
        float4 w1 = *(const float4*)(W1 + k * 64 + j4);
        float4 w2 = *(const float4*)(W2 + k * 64 + j4);
        *(float4*)(&W1s[k * 68 + j4]) = w1;
        *(float4*)(&W2s[k * 68 + j4]) = w2;
    }
    if (t < 64)       b1s[t]      = b1[t];
    else if (t < 128) b2s[t - 64] = b2[t - 64];

    const float epsv = 1.0f + epsp[0];

    // stage x rows: node-major xs[n*65 + k]
    #pragma unroll
    for (int i = 0; i < 4; ++i) {
        int n  = (t >> 4) + i * 16;
        int k4 = (t & 15) << 2;
        int gn = nb + n;
        float4 f = make_float4(0.f, 0.f, 0.f, 0.f);
        float4 g = make_float4(0.f, 0.f, 0.f, 0.f);
        if (gn < N_NODES) {
            f = *(const float4*)(feat  + (size_t)gn * 64 + k4);
            g = *(const float4*)(neigh + (size_t)gn * 64 + k4);
        }
        xs[n * 65 + k4 + 0] = epsv * f.x + g.x;
        xs[n * 65 + k4 + 1] = epsv * f.y + g.y;
        xs[n * 65 + k4 + 2] = epsv * f.z + g.z;
        xs[n * 65 + k4 + 3] = epsv * f.w + g.w;
    }
    __syncthreads();

    const int n0 = (t & 15) << 2;
    const int j0 = (t >> 4) << 2;

    const float* xr0 = &xs[(n0 + 0) * 65];
    const float* xr1 = &xs[(n0 + 1) * 65];
    const float* xr2 = &xs[(n0 + 2) * 65];
    const float* xr3 = &xs[(n0 + 3) * 65];

    float acc[4][4];
    #pragma unroll
    for (int a = 0; a < 4; ++a)
        #pragma unroll
        for (int b = 0; b < 4; ++b)
            acc[a][b] = b1s[j0 + b];

    #pragma unroll 8
    for (int k = 0; k < 64; ++k) {
        const float4 w = *(const float4*)(&W1s[k * 68 + j0]);
        const float x0 = xr0[k], x1 = xr1[k], x2 = xr2[k], x3 = xr3[k];
        acc[0][0] = fmaf(x0, w.x, acc[0][0]);
        acc[0][1] = fmaf(x0, w.y, acc[0][1]);
        acc[0][2] = fmaf(x0, w.z, acc[0][2]);
        acc[0][3] = fmaf(x0, w.w, acc[0][3]);
        acc[1][0] = fmaf(x1, w.x, acc[1][0]);
        acc[1][1] = fmaf(x1, w.y, acc[1][1]);
        acc[1][2] = fmaf(x1, w.z, acc[1][2]);
        acc[1][3] = fmaf(x1, w.w, acc[1][3]);
        acc[2][0] = fmaf(x2, w.x, acc[2][0]);
        acc[2][1] = fmaf(x2, w.y, acc[2][1]);
        acc[2][2] = fmaf(x2, w.z, acc[2][2]);
        acc[2][3] = fmaf(x2, w.w, acc[2][3]);
        acc[3][0] = fmaf(x3, w.x, acc[3][0]);
        acc[3][1] = fmaf(x3, w.y, acc[3][1]);
        acc[3][2] = fmaf(x3, w.z, acc[3][2]);
        acc[3][3] = fmaf(x3, w.w, acc[3][3]);
    }

    __syncthreads();   // all GEMM1 reads of xs done
    #pragma unroll
    for (int a = 0; a < 4; ++a)
        #pragma unroll
        for (int b = 0; b < 4; ++b)
            xs[(n0 + a) * 65 + j0 + b] = fmaxf(acc[a][b], 0.0f);
    __syncthreads();   // t-matrix visible to all

    float acc2[4][4];
    #pragma unroll
    for (int a = 0; a < 4; ++a)
        #pragma unroll
        for (int b = 0; b < 4; ++b)
            acc2[a][b] = b2s[j0 + b];

    #pragma unroll 8
    for (int k = 0; k < 64; ++k) {
        const float4 w = *(const float4*)(&W2s[k * 68 + j0]);
        const float x0 = xr0[k], x1 = xr1[k], x2 = xr2[k], x3 = xr3[k];
        acc2[0][0] = fmaf(x0, w.x, acc2[0][0]);
        acc2[0][1] = fmaf(x0, w.y, acc2[0][1]);
        acc2[0][2] = fmaf(x0, w.z, acc2[0][2]);
        acc2[0][3] = fmaf(x0, w.w, acc2[0][3]);
        acc2[1][0] = fmaf(x1, w.x, acc2[1][0]);
        acc2[1][1] = fmaf(x1, w.y, acc2[1][1]);
        acc2[1][2] = fmaf(x1, w.z, acc2[1][2]);
        acc2[1][3] = fmaf(x1, w.w, acc2[1][3]);
        acc2[2][0] = fmaf(x2, w.x, acc2[2][0]);
        acc2[2][1] = fmaf(x2, w.y, acc2[2][1]);
        acc2[2][2] = fmaf(x2, w.z, acc2[2][2]);
        acc2[2][3] = fmaf(x2, w.w, acc2[2][3]);
        acc2[3][0] = fmaf(x3, w.x, acc2[3][0]);
        acc2[3][1] = fmaf(x3, w.y, acc2[3][1]);
        acc2[3][2] = fmaf(x3, w.z, acc2[3][2]);
        acc2[3][3] = fmaf(x3, w.w, acc2[3][3]);
    }

    // epilogue: store h2, accumulate BN partials
    float psum[4] = {0.f, 0.f, 0.f, 0.f};
    float psq[4]  = {0.f, 0.f, 0.f, 0.f};
    #pragma unroll
    for (int a = 0; a < 4; ++a) {
        int gn = nb + n0 + a;
        if (gn < N_NODES) {
            float4 h;
            h.x = acc2[a][0]; h.y = acc2[a][1]; h.z = acc2[a][2]; h.w = acc2[a][3];
            *(float4*)(h2out + (size_t)gn * 64 + j0) = h;
            psum[0] += h.x; psq[0] += h.x * h.x;
            psum[1] += h.y; psq[1] += h.y * h.y;
            psum[2] += h.z; psq[2] += h.z * h.z;
            psum[3] += h.w; psq[3] += h.w * h.w;
        }
    }
    // reduce over the 16 lanes (consecutive) sharing this j0 group
    #pragma unroll
    for (int off = 8; off >= 1; off >>= 1) {
        #pragma unroll
        for (int b = 0; b < 4; ++b) {
            psum[b] += __shfl_down(psum[b], off, 16);
            psq[b]  += __shfl_down(psq[b],  off, 16);
        }
    }
    if ((t & 15) == 0) {
        float* sp = stats8 + (size_t)(blockIdx.x & 7) * 128;
        #pragma unroll
        for (int b = 0; b < 4; ++b) {
            unsafeAtomicAdd(sp + j0 + b,      psum[b]);
            unsafeAtomicAdd(sp + 64 + j0 + b, psq[b]);
        }
    }
}

// ---------------------------------------------------------------------------
// K2.5: fold the 8 stat shards, produce scale/shift per column.
// ---------------------------------------------------------------------------
__global__ void bnstats_k(const float* __restrict__ stats8,
                          const float* __restrict__ gamma,
                          const float* __restrict__ beta,
                          float* __restrict__ sf)
{
    int j = threadIdx.x;  // 64 threads
    float s = 0.f, q = 0.f;
    #pragma unroll
    for (int c = 0; c < 8; ++c) {
        s += stats8[c * 128 + j];
        q += stats8[c * 128 + 64 + j];
    }
    const float invN = 1.0f / (float)N_NODES;
    float mean  = s * invN;
    float var   = q * invN - mean * mean;
    float scale = gamma[j] * rsqrtf(var + BN_EPS);
    sf[j]      = scale;
    sf[64 + j] = beta[j] - mean * scale;
}

// ---------------------------------------------------------------------------
// K3: out = relu(h2*scale + shift) + feat  (h2 lives in d_out, in-place)
// ---------------------------------------------------------------------------
__global__ __launch_bounds__(256) void finish_k(
    const float* __restrict__ feat, const float* __restrict__ sf,
    float* __restrict__ out)
{
    __shared__ float scs[64], shs[64];
    if (threadIdx.x < 64) {
        scs[threadIdx.x] = sf[threadIdx.x];
        shs[threadIdx.x] = sf[64 + threadIdx.x];
    }
    __syncthreads();
    size_t i = (size_t)blockIdx.x * 256 + threadIdx.x;   // float4 index
    if (i < (size_t)N_NODES * D / 4) {
        int j = (int)((i * 4) & 63);
        float4 h = *(float4*)(out + i * 4);
        float4 f = *(const float4*)(feat + i * 4);
        h.x = fmaxf(fmaf(h.x, scs[j + 0], shs[j + 0]), 0.f) + f.x;
        h.y = fmaxf(fmaf(h.y, scs[j + 1], shs[j + 1]), 0.f) + f.y;
        h.z = fmaxf(fmaf(h.z, scs[j + 2], shs[j + 2]), 0.f) + f.z;
        h.w = fmaxf(fmaf(h.w, scs[j + 3], shs[j + 3]), 0.f) + f.w;
        *(float4*)(out + i * 4) = h;
    }
}

extern "C" void kernel_launch(void* const* d_in, const int* in_sizes, int n_in,
                              void* d_out, int out_size, void* d_ws, size_t ws_size,
                              hipStream_t stream)
{
    const float* feat  = (const float*)d_in[0];
    const int*   src   = (const int*)d_in[1];
    const int*   dst   = (const int*)d_in[2];
    const float* eps   = (const float*)d_in[3];
    const float* W1    = (const float*)d_in[4];
    const float* b1    = (const float*)d_in[5];
    const float* W2    = (const float*)d_in[6];
    const float* b2    = (const float*)d_in[7];
    const float* gamma = (const float*)d_in[8];
    const float* beta  = (const float*)d_in[9];
    float* out = (float*)d_out;

    float* neigh  = (float*)d_ws;                       // N_NODES*D floats
    float* stats8 = neigh + (size_t)N_NODES * D;        // 8*128 floats
    float* sf     = stats8 + 1024;                      // 128 floats

    // zero neigh + stats shards
    hipMemsetAsync(d_ws, 0, (size_t)N_NODES * D * sizeof(float) + 1024 * sizeof(float), stream);

    scatter_k<<<(N_EDGES * 16) / 256, 256, 0, stream>>>(feat, src, dst, neigh);
    mlp_k<<<(N_NODES + 63) / 64, 256, 0, stream>>>(feat, neigh, eps, W1, b1, W2, b2, out, stats8);
    bnstats_k<<<1, 64, 0, stream>>>(stats8, gamma, beta, sf);
    finish_k<<<(N_NODES * D / 4 + 255) / 256, 256, 0, stream>>>(feat, sf, out);
}

// Round 2
// 683.622 us; speedup vs baseline: 2.1981x; 2.1981x over previous
//
#include <hip/hip_runtime.h>

#define N_NODES 100000
#define N_EDGES 1600000
#define D 64
#define BN_EPS 1e-5f

// ---------------------------------------------------------------------------
// K0: degree histogram. deg must be pre-zeroed.
// ---------------------------------------------------------------------------
__global__ __launch_bounds__(256) void hist_k(
    const int* __restrict__ dst, int* __restrict__ deg)
{
    int e = blockIdx.x * 256 + threadIdx.x;
    if (e < N_EDGES) atomicAdd(&deg[dst[e]], 1);
}

// ---------------------------------------------------------------------------
// K0.5: single-block exclusive scan of deg -> rowptr (and cursor copy).
// 1024 threads x 98 elements each covers 100000.
// ---------------------------------------------------------------------------
#define SCAN_ITEMS 98
__global__ __launch_bounds__(1024) void scan_k(
    const int* __restrict__ deg, int* __restrict__ rowptr,
    int* __restrict__ cursor)
{
    __shared__ int part[1024];
    const int t = threadIdx.x;
    const int base = t * SCAN_ITEMS;
    int s = 0;
    #pragma unroll 4
    for (int i = 0; i < SCAN_ITEMS; ++i) {
        int idx = base + i;
        if (idx < N_NODES) s += deg[idx];
    }
    part[t] = s;
    __syncthreads();
    // Hillis-Steele inclusive scan over 1024 partials
    for (int off = 1; off < 1024; off <<= 1) {
        int v = part[t];
        int u = (t >= off) ? part[t - off] : 0;
        __syncthreads();
        part[t] = v + u;
        __syncthreads();
    }
    int run = (t == 0) ? 0 : part[t - 1];
    for (int i = 0; i < SCAN_ITEMS; ++i) {
        int idx = base + i;
        if (idx < N_NODES) {
            rowptr[idx] = run;
            cursor[idx] = run;
            run += deg[idx];
        }
    }
    if (t == 1023) rowptr[N_NODES] = part[1023];
}

// ---------------------------------------------------------------------------
// K0.75: place each edge's src into its dst's CSR slot.
// ---------------------------------------------------------------------------
__global__ __launch_bounds__(256) void fill_k(
    const int* __restrict__ src, const int* __restrict__ dst,
    int* __restrict__ cursor, int* __restrict__ col)
{
    int e = blockIdx.x * 256 + threadIdx.x;
    if (e < N_EDGES) {
        int d = dst[e];
        int slot = atomicAdd(&cursor[d], 1);
        col[slot] = src[e];
    }
}

// ---------------------------------------------------------------------------
// K1: gather-sum. One 64-lane wave per node; lane = feature column.
// Each edge is one coalesced 256B read of feat[src]; no atomics.
// Writes every neigh row (degree-0 nodes get 0) -> no neigh memset needed.
// ---------------------------------------------------------------------------
__global__ __launch_bounds__(256) void gather_k(
    const float* __restrict__ feat, const int* __restrict__ rowptr,
    const int* __restrict__ col, float* __restrict__ neigh)
{
    int node = blockIdx.x * 4 + (threadIdx.x >> 6);
    int lane = threadIdx.x & 63;
    if (node >= N_NODES) return;
    int lo = rowptr[node];
    int hi = rowptr[node + 1];
    float acc = 0.f;
    int e = lo;
    // unroll by 2 for two outstanding loads
    for (; e + 1 < hi; e += 2) {
        int s0 = col[e];
        int s1 = col[e + 1];
        float a = feat[(size_t)s0 * D + lane];
        float b = feat[(size_t)s1 * D + lane];
        acc += a;
        acc += b;
    }
    if (e < hi) acc += feat[(size_t)col[e] * D + lane];
    neigh[(size_t)node * D + lane] = acc;
}

// ---------------------------------------------------------------------------
// K2: per 64-node tile: x = (1+eps)*feat + neigh; h2 = relu(x@W1+b1)@W2+b2.
// Writes h2 to h2out (d_out used as temp), accumulates BN partial sums into
// stats8 (8 shards of [sum[64], sumsq[64]]).
// ---------------------------------------------------------------------------
__global__ __launch_bounds__(256) void mlp_k(
    const float* __restrict__ feat, const float* __restrict__ neigh,
    const float* __restrict__ epsp,
    const float* __restrict__ W1, const float* __restrict__ b1,
    const float* __restrict__ W2, const float* __restrict__ b2,
    float* __restrict__ h2out, float* __restrict__ stats8)
{
    __shared__ float W1s[64 * 68];
    __shared__ float W2s[64 * 68];
    __shared__ float xs[64 * 65];
    __shared__ float b1s[64], b2s[64];

    const int t  = threadIdx.x;
    const int nb = blockIdx.x * 64;

    #pragma unroll
    for (int i = 0; i < 4; ++i) {
        int l  = t + i * 256;
        int k  = l >> 4;
        int j4 = (l & 15) << 2;
        float4 w1 = *(const float4*)(W1 + k * 64 + j4);
        float4 w2 = *(const float4*)(W2 + k * 64 + j4);
        *(float4*)(&W1s[k * 68 + j4]) = w1;
        *(float4*)(&W2s[k * 68 + j4]) = w2;
    }
    if (t < 64)       b1s[t]      = b1[t];
    else if (t < 128) b2s[t - 64] = b2[t - 64];

    const float epsv = 1.0f + epsp[0];

    #pragma unroll
    for (int i = 0; i < 4; ++i) {
        int n  = (t >> 4) + i * 16;
        int k4 = (t & 15) << 2;
        int gn = nb + n;
        float4 f = make_float4(0.f, 0.f, 0.f, 0.f);
        float4 g = make_float4(0.f, 0.f, 0.f, 0.f);
        if (gn < N_NODES) {
            f = *(const float4*)(feat  + (size_t)gn * 64 + k4);
            g = *(const float4*)(neigh + (size_t)gn * 64 + k4);
        }
        xs[n * 65 + k4 + 0] = epsv * f.x + g.x;
        xs[n * 65 + k4 + 1] = epsv * f.y + g.y;
        xs[n * 65 + k4 + 2] = epsv * f.z + g.z;
        xs[n * 65 + k4 + 3] = epsv * f.w + g.w;
    }
    __syncthreads();

    const int n0 = (t & 15) << 2;
    const int j0 = (t >> 4) << 2;

    const float* xr0 = &xs[(n0 + 0) * 65];
    const float* xr1 = &xs[(n0 + 1) * 65];
    const float* xr2 = &xs[(n0 + 2) * 65];
    const float* xr3 = &xs[(n0 + 3) * 65];

    float acc[4][4];
    #pragma unroll
    for (int a = 0; a < 4; ++a)
        #pragma unroll
        for (int b = 0; b < 4; ++b)
            acc[a][b] = b1s[j0 + b];

    #pragma unroll 8
    for (int k = 0; k < 64; ++k) {
        const float4 w = *(const float4*)(&W1s[k * 68 + j0]);
        const float x0 = xr0[k], x1 = xr1[k], x2 = xr2[k], x3 = xr3[k];
        acc[0][0] = fmaf(x0, w.x, acc[0][0]);
        acc[0][1] = fmaf(x0, w.y, acc[0][1]);
        acc[0][2] = fmaf(x0, w.z, acc[0][2]);
        acc[0][3] = fmaf(x0, w.w, acc[0][3]);
        acc[1][0] = fmaf(x1, w.x, acc[1][0]);
        acc[1][1] = fmaf(x1, w.y, acc[1][1]);
        acc[1][2] = fmaf(x1, w.z, acc[1][2]);
        acc[1][3] = fmaf(x1, w.w, acc[1][3]);
        acc[2][0] = fmaf(x2, w.x, acc[2][0]);
        acc[2][1] = fmaf(x2, w.y, acc[2][1]);
        acc[2][2] = fmaf(x2, w.z, acc[2][2]);
        acc[2][3] = fmaf(x2, w.w, acc[2][3]);
        acc[3][0] = fmaf(x3, w.x, acc[3][0]);
        acc[3][1] = fmaf(x3, w.y, acc[3][1]);
        acc[3][2] = fmaf(x3, w.z, acc[3][2]);
        acc[3][3] = fmaf(x3, w.w, acc[3][3]);
    }

    __syncthreads();
    #pragma unroll
    for (int a = 0; a < 4; ++a)
        #pragma unroll
        for (int b = 0; b < 4; ++b)
            xs[(n0 + a) * 65 + j0 + b] = fmaxf(acc[a][b], 0.0f);
    __syncthreads();

    float acc2[4][4];
    #pragma unroll
    for (int a = 0; a < 4; ++a)
        #pragma unroll
        for (int b = 0; b < 4; ++b)
            acc2[a][b] = b2s[j0 + b];

    #pragma unroll 8
    for (int k = 0; k < 64; ++k) {
        const float4 w = *(const float4*)(&W2s[k * 68 + j0]);
        const float x0 = xr0[k], x1 = xr1[k], x2 = xr2[k], x3 = xr3[k];
        acc2[0][0] = fmaf(x0, w.x, acc2[0][0]);
        acc2[0][1] = fmaf(x0, w.y, acc2[0][1]);
        acc2[0][2] = fmaf(x0, w.z, acc2[0][2]);
        acc2[0][3] = fmaf(x0, w.w, acc2[0][3]);
        acc2[1][0] = fmaf(x1, w.x, acc2[1][0]);
        acc2[1][1] = fmaf(x1, w.y, acc2[1][1]);
        acc2[1][2] = fmaf(x1, w.z, acc2[1][2]);
        acc2[1][3] = fmaf(x1, w.w, acc2[1][3]);
        acc2[2][0] = fmaf(x2, w.x, acc2[2][0]);
        acc2[2][1] = fmaf(x2, w.y, acc2[2][1]);
        acc2[2][2] = fmaf(x2, w.z, acc2[2][2]);
        acc2[2][3] = fmaf(x2, w.w, acc2[2][3]);
        acc2[3][0] = fmaf(x3, w.x, acc2[3][0]);
        acc2[3][1] = fmaf(x3, w.y, acc2[3][1]);
        acc2[3][2] = fmaf(x3, w.z, acc2[3][2]);
        acc2[3][3] = fmaf(x3, w.w, acc2[3][3]);
    }

    float psum[4] = {0.f, 0.f, 0.f, 0.f};
    float psq[4]  = {0.f, 0.f, 0.f, 0.f};
    #pragma unroll
    for (int a = 0; a < 4; ++a) {
        int gn = nb + n0 + a;
        if (gn < N_NODES) {
            float4 h;
            h.x = acc2[a][0]; h.y = acc2[a][1]; h.z = acc2[a][2]; h.w = acc2[a][3];
            *(float4*)(h2out + (size_t)gn * 64 + j0) = h;
            psum[0] += h.x; psq[0] += h.x * h.x;
            psum[1] += h.y; psq[1] += h.y * h.y;
            psum[2] += h.z; psq[2] += h.z * h.z;
            psum[3] += h.w; psq[3] += h.w * h.w;
        }
    }
    #pragma unroll
    for (int off = 8; off >= 1; off >>= 1) {
        #pragma unroll
        for (int b = 0; b < 4; ++b) {
            psum[b] += __shfl_down(psum[b], off, 16);
            psq[b]  += __shfl_down(psq[b],  off, 16);
        }
    }
    if ((t & 15) == 0) {
        float* sp = stats8 + (size_t)(blockIdx.x & 7) * 128;
        #pragma unroll
        for (int b = 0; b < 4; ++b) {
            unsafeAtomicAdd(sp + j0 + b,      psum[b]);
            unsafeAtomicAdd(sp + 64 + j0 + b, psq[b]);
        }
    }
}

// ---------------------------------------------------------------------------
// K2.5: fold the 8 stat shards, produce scale/shift per column.
// ---------------------------------------------------------------------------
__global__ void bnstats_k(const float* __restrict__ stats8,
                          const float* __restrict__ gamma,
                          const float* __restrict__ beta,
                          float* __restrict__ sf)
{
    int j = threadIdx.x;  // 64 threads
    float s = 0.f, q = 0.f;
    #pragma unroll
    for (int c = 0; c < 8; ++c) {
        s += stats8[c * 128 + j];
        q += stats8[c * 128 + 64 + j];
    }
    const float invN = 1.0f / (float)N_NODES;
    float mean  = s * invN;
    float var   = q * invN - mean * mean;
    float scale = gamma[j] * rsqrtf(var + BN_EPS);
    sf[j]      = scale;
    sf[64 + j] = beta[j] - mean * scale;
}

// ---------------------------------------------------------------------------
// K3: out = relu(h2*scale + shift) + feat  (h2 lives in d_out, in-place)
// ---------------------------------------------------------------------------
__global__ __launch_bounds__(256) void finish_k(
    const float* __restrict__ feat, const float* __restrict__ sf,
    float* __restrict__ out)
{
    __shared__ float scs[64], shs[64];
    if (threadIdx.x < 64) {
        scs[threadIdx.x] = sf[threadIdx.x];
        shs[threadIdx.x] = sf[64 + threadIdx.x];
    }
    __syncthreads();
    size_t i = (size_t)blockIdx.x * 256 + threadIdx.x;   // float4 index
    if (i < (size_t)N_NODES * D / 4) {
        int j = (int)((i * 4) & 63);
        float4 h = *(float4*)(out + i * 4);
        float4 f = *(const float4*)(feat + i * 4);
        h.x = fmaxf(fmaf(h.x, scs[j + 0], shs[j + 0]), 0.f) + f.x;
        h.y = fmaxf(fmaf(h.y, scs[j + 1], shs[j + 1]), 0.f) + f.y;
        h.z = fmaxf(fmaf(h.z, scs[j + 2], shs[j + 2]), 0.f) + f.z;
        h.w = fmaxf(fmaf(h.w, scs[j + 3], shs[j + 3]), 0.f) + f.w;
        *(float4*)(out + i * 4) = h;
    }
}

extern "C" void kernel_launch(void* const* d_in, const int* in_sizes, int n_in,
                              void* d_out, int out_size, void* d_ws, size_t ws_size,
                              hipStream_t stream)
{
    const float* feat  = (const float*)d_in[0];
    const int*   src   = (const int*)d_in[1];
    const int*   dst   = (const int*)d_in[2];
    const float* eps   = (const float*)d_in[3];
    const float* W1    = (const float*)d_in[4];
    const float* b1    = (const float*)d_in[5];
    const float* W2    = (const float*)d_in[6];
    const float* b2    = (const float*)d_in[7];
    const float* gamma = (const float*)d_in[8];
    const float* beta  = (const float*)d_in[9];
    float* out = (float*)d_out;

    // workspace layout (all 4-byte typed; neigh first for 16B alignment)
    float* neigh  = (float*)d_ws;                         // N_NODES*64 floats
    int*   col    = (int*)(neigh + (size_t)N_NODES * D);  // N_EDGES ints
    int*   rowptr = col + N_EDGES;                        // N_NODES+1 ints
    int*   cursor = rowptr + (N_NODES + 1);               // N_NODES ints
    int*   deg    = cursor + N_NODES;                     // N_NODES ints
    float* stats8 = (float*)(deg + N_NODES);              // 8*128 floats
    float* sf     = stats8 + 1024;                        // 128 floats

    // zero deg + stats8 (contiguous)
    hipMemsetAsync(deg, 0, (size_t)N_NODES * sizeof(int) + 1024 * sizeof(float), stream);

    hist_k<<<(N_EDGES + 255) / 256, 256, 0, stream>>>(dst, deg);
    scan_k<<<1, 1024, 0, stream>>>(deg, rowptr, cursor);
    fill_k<<<(N_EDGES + 255) / 256, 256, 0, stream>>>(src, dst, cursor, col);
    gather_k<<<(N_NODES + 3) / 4, 256, 0, stream>>>(feat, rowptr, col, neigh);
    mlp_k<<<(N_NODES + 63) / 64, 256, 0, stream>>>(feat, neigh, eps, W1, b1, W2, b2, out, stats8);
    bnstats_k<<<1, 64, 0, stream>>>(stats8, gamma, beta, sf);
    finish_k<<<(N_NODES * D / 4 + 255) / 256, 256, 0, stream>>>(feat, sf, out);
}

// Round 3
// 395.351 us; speedup vs baseline: 3.8008x; 1.7291x over previous
//
#include <hip/hip_runtime.h>

#define N_NODES 100000
#define N_EDGES 1600000
#define D 64
#define BN_EPS 1e-5f
#define NB ((N_NODES + 255) / 256)   // 391 scan blocks

// ---------------------------------------------------------------------------
// K0: degree histogram. deg must be pre-zeroed.
// ---------------------------------------------------------------------------
__global__ __launch_bounds__(256) void hist_k(
    const int* __restrict__ dst, int* __restrict__ deg)
{
    int e = blockIdx.x * 256 + threadIdx.x;
    if (e < N_EDGES) atomicAdd(&deg[dst[e]], 1);
}

// ---------------------------------------------------------------------------
// Scan phase A: per-block (256-elem) sums of deg.
// ---------------------------------------------------------------------------
__global__ __launch_bounds__(256) void blocksum_k(
    const int* __restrict__ deg, int* __restrict__ bs)
{
    int i = blockIdx.x * 256 + threadIdx.x;
    int v = (i < N_NODES) ? deg[i] : 0;
    #pragma unroll
    for (int off = 32; off >= 1; off >>= 1) v += __shfl_down(v, off, 64);
    __shared__ int s[4];
    if ((threadIdx.x & 63) == 0) s[threadIdx.x >> 6] = v;
    __syncthreads();
    if (threadIdx.x == 0) bs[blockIdx.x] = s[0] + s[1] + s[2] + s[3];
}

// ---------------------------------------------------------------------------
// Scan phase B: one block scans the NB block sums -> exclusive offsets.
// ---------------------------------------------------------------------------
__global__ __launch_bounds__(512) void scanblk_k(
    const int* __restrict__ bs, int* __restrict__ boff)
{
    __shared__ int part[512];
    int t = threadIdx.x;
    int v = (t < NB) ? bs[t] : 0;
    part[t] = v;
    __syncthreads();
    for (int off = 1; off < 512; off <<= 1) {
        int x = part[t];
        int u = (t >= off) ? part[t - off] : 0;
        __syncthreads();
        part[t] = x + u;
        __syncthreads();
    }
    if (t < NB) boff[t] = part[t] - v;   // exclusive
}

// ---------------------------------------------------------------------------
// Scan phase C: block-local exclusive scan + block offset -> rowptr/cursor.
// ---------------------------------------------------------------------------
__global__ __launch_bounds__(256) void scan_out_k(
    const int* __restrict__ deg, const int* __restrict__ boff,
    int* __restrict__ rowptr, int* __restrict__ cursor)
{
    int i = blockIdx.x * 256 + threadIdx.x;
    int v = (i < N_NODES) ? deg[i] : 0;
    int lane = threadIdx.x & 63;
    int w = threadIdx.x >> 6;
    int x = v;
    #pragma unroll
    for (int off = 1; off < 64; off <<= 1) {
        int u = __shfl_up(x, off, 64);
        if (lane >= off) x += u;
    }
    __shared__ int wsum[4];
    if (lane == 63) wsum[w] = x;
    __syncthreads();
    int woff = 0;
    #pragma unroll
    for (int j = 0; j < 4; ++j) woff += (j < w) ? wsum[j] : 0;
    int excl = boff[blockIdx.x] + woff + x - v;
    if (i < N_NODES) {
        rowptr[i] = excl;
        cursor[i] = excl;
        if (i == N_NODES - 1) rowptr[N_NODES] = excl + v;
    }
}

// ---------------------------------------------------------------------------
// K0.75: place each edge's src into its dst's CSR slot.
// ---------------------------------------------------------------------------
__global__ __launch_bounds__(256) void fill_k(
    const int* __restrict__ src, const int* __restrict__ dst,
    int* __restrict__ cursor, int* __restrict__ col)
{
    int e = blockIdx.x * 256 + threadIdx.x;
    if (e < N_EDGES) {
        int d = dst[e];
        int slot = atomicAdd(&cursor[d], 1);
        col[slot] = src[e];
    }
}

// ---------------------------------------------------------------------------
// K1: gather-sum. One wave per node. Lanes form 4 groups of 16; group g
// handles edges lo+g, lo+g+4, ... Each lane loads float4 (16B) -> one edge
// row = 16 lanes x 16B = 256B coalesced. Final 2-step shfl_xor merges groups.
// ---------------------------------------------------------------------------
__global__ __launch_bounds__(256) void gather_k(
    const float* __restrict__ feat, const int* __restrict__ rowptr,
    const int* __restrict__ col, float* __restrict__ neigh)
{
    int node = blockIdx.x * 4 + (threadIdx.x >> 6);
    int lane = threadIdx.x & 63;
    if (node >= N_NODES) return;
    int g = lane >> 4;            // edge group 0..3
    int c = (lane & 15) << 2;     // column base
    int lo = rowptr[node];
    int hi = rowptr[node + 1];
    float ax = 0.f, ay = 0.f, az = 0.f, aw = 0.f;
    int e = lo + g;
    for (; e + 4 < hi; e += 8) {
        int s0 = col[e];
        int s1 = col[e + 4];
        float4 v0 = *(const float4*)(feat + (size_t)s0 * D + c);
        float4 v1 = *(const float4*)(feat + (size_t)s1 * D + c);
        ax += v0.x; ay += v0.y; az += v0.z; aw += v0.w;
        ax += v1.x; ay += v1.y; az += v1.z; aw += v1.w;
    }
    if (e < hi) {
        float4 v = *(const float4*)(feat + (size_t)col[e] * D + c);
        ax += v.x; ay += v.y; az += v.z; aw += v.w;
    }
    #pragma unroll
    for (int off = 16; off <= 32; off <<= 1) {
        ax += __shfl_xor(ax, off, 64);
        ay += __shfl_xor(ay, off, 64);
        az += __shfl_xor(az, off, 64);
        aw += __shfl_xor(aw, off, 64);
    }
    if (g == 0) {
        float4 r; r.x = ax; r.y = ay; r.z = az; r.w = aw;
        *(float4*)(neigh + (size_t)node * D + c) = r;
    }
}

// ---------------------------------------------------------------------------
// K2: per 64-node tile: x = (1+eps)*feat + neigh; h2 = relu(x@W1+b1)@W2+b2.
// Writes h2 to d_out (temp), accumulates BN partials into stats8.
// ---------------------------------------------------------------------------
__global__ __launch_bounds__(256) void mlp_k(
    const float* __restrict__ feat, const float* __restrict__ neigh,
    const float* __restrict__ epsp,
    const float* __restrict__ W1, const float* __restrict__ b1,
    const float* __restrict__ W2, const float* __restrict__ b2,
    float* __restrict__ h2out, float* __restrict__ stats8)
{
    __shared__ float W1s[64 * 68];
    __shared__ float W2s[64 * 68];
    __shared__ float xs[64 * 65];
    __shared__ float b1s[64], b2s[64];

    const int t  = threadIdx.x;
    const int nb = blockIdx.x * 64;

    #pragma unroll
    for (int i = 0; i < 4; ++i) {
        int l  = t + i * 256;
        int k  = l >> 4;
        int j4 = (l & 15) << 2;
        float4 w1 = *(const float4*)(W1 + k * 64 + j4);
        float4 w2 = *(const float4*)(W2 + k * 64 + j4);
        *(float4*)(&W1s[k * 68 + j4]) = w1;
        *(float4*)(&W2s[k * 68 + j4]) = w2;
    }
    if (t < 64)       b1s[t]      = b1[t];
    else if (t < 128) b2s[t - 64] = b2[t - 64];

    const float epsv = 1.0f + epsp[0];

    #pragma unroll
    for (int i = 0; i < 4; ++i) {
        int n  = (t >> 4) + i * 16;
        int k4 = (t & 15) << 2;
        int gn = nb + n;
        float4 f = make_float4(0.f, 0.f, 0.f, 0.f);
        float4 g = make_float4(0.f, 0.f, 0.f, 0.f);
        if (gn < N_NODES) {
            f = *(const float4*)(feat  + (size_t)gn * 64 + k4);
            g = *(const float4*)(neigh + (size_t)gn * 64 + k4);
        }
        xs[n * 65 + k4 + 0] = epsv * f.x + g.x;
        xs[n * 65 + k4 + 1] = epsv * f.y + g.y;
        xs[n * 65 + k4 + 2] = epsv * f.z + g.z;
        xs[n * 65 + k4 + 3] = epsv * f.w + g.w;
    }
    __syncthreads();

    const int n0 = (t & 15) << 2;
    const int j0 = (t >> 4) << 2;

    const float* xr0 = &xs[(n0 + 0) * 65];
    const float* xr1 = &xs[(n0 + 1) * 65];
    const float* xr2 = &xs[(n0 + 2) * 65];
    const float* xr3 = &xs[(n0 + 3) * 65];

    float acc[4][4];
    #pragma unroll
    for (int a = 0; a < 4; ++a)
        #pragma unroll
        for (int b = 0; b < 4; ++b)
            acc[a][b] = b1s[j0 + b];

    #pragma unroll 8
    for (int k = 0; k < 64; ++k) {
        const float4 w = *(const float4*)(&W1s[k * 68 + j0]);
        const float x0 = xr0[k], x1 = xr1[k], x2 = xr2[k], x3 = xr3[k];
        acc[0][0] = fmaf(x0, w.x, acc[0][0]);
        acc[0][1] = fmaf(x0, w.y, acc[0][1]);
        acc[0][2] = fmaf(x0, w.z, acc[0][2]);
        acc[0][3] = fmaf(x0, w.w, acc[0][3]);
        acc[1][0] = fmaf(x1, w.x, acc[1][0]);
        acc[1][1] = fmaf(x1, w.y, acc[1][1]);
        acc[1][2] = fmaf(x1, w.z, acc[1][2]);
        acc[1][3] = fmaf(x1, w.w, acc[1][3]);
        acc[2][0] = fmaf(x2, w.x, acc[2][0]);
        acc[2][1] = fmaf(x2, w.y, acc[2][1]);
        acc[2][2] = fmaf(x2, w.z, acc[2][2]);
        acc[2][3] = fmaf(x2, w.w, acc[2][3]);
        acc[3][0] = fmaf(x3, w.x, acc[3][0]);
        acc[3][1] = fmaf(x3, w.y, acc[3][1]);
        acc[3][2] = fmaf(x3, w.z, acc[3][2]);
        acc[3][3] = fmaf(x3, w.w, acc[3][3]);
    }

    __syncthreads();
    #pragma unroll
    for (int a = 0; a < 4; ++a)
        #pragma unroll
        for (int b = 0; b < 4; ++b)
            xs[(n0 + a) * 65 + j0 + b] = fmaxf(acc[a][b], 0.0f);
    __syncthreads();

    float acc2[4][4];
    #pragma unroll
    for (int a = 0; a < 4; ++a)
        #pragma unroll
        for (int b = 0; b < 4; ++b)
            acc2[a][b] = b2s[j0 + b];

    #pragma unroll 8
    for (int k = 0; k < 64; ++k) {
        const float4 w = *(const float4*)(&W2s[k * 68 + j0]);
        const float x0 = xr0[k], x1 = xr1[k], x2 = xr2[k], x3 = xr3[k];
        acc2[0][0] = fmaf(x0, w.x, acc2[0][0]);
        acc2[0][1] = fmaf(x0, w.y, acc2[0][1]);
        acc2[0][2] = fmaf(x0, w.z, acc2[0][2]);
        acc2[0][3] = fmaf(x0, w.w, acc2[0][3]);
        acc2[1][0] = fmaf(x1, w.x, acc2[1][0]);
        acc2[1][1] = fmaf(x1, w.y, acc2[1][1]);
        acc2[1][2] = fmaf(x1, w.z, acc2[1][2]);
        acc2[1][3] = fmaf(x1, w.w, acc2[1][3]);
        acc2[2][0] = fmaf(x2, w.x, acc2[2][0]);
        acc2[2][1] = fmaf(x2, w.y, acc2[2][1]);
        acc2[2][2] = fmaf(x2, w.z, acc2[2][2]);
        acc2[2][3] = fmaf(x2, w.w, acc2[2][3]);
        acc2[3][0] = fmaf(x3, w.x, acc2[3][0]);
        acc2[3][1] = fmaf(x3, w.y, acc2[3][1]);
        acc2[3][2] = fmaf(x3, w.z, acc2[3][2]);
        acc2[3][3] = fmaf(x3, w.w, acc2[3][3]);
    }

    float psum[4] = {0.f, 0.f, 0.f, 0.f};
    float psq[4]  = {0.f, 0.f, 0.f, 0.f};
    #pragma unroll
    for (int a = 0; a < 4; ++a) {
        int gn = nb + n0 + a;
        if (gn < N_NODES) {
            float4 h;
            h.x = acc2[a][0]; h.y = acc2[a][1]; h.z = acc2[a][2]; h.w = acc2[a][3];
            *(float4*)(h2out + (size_t)gn * 64 + j0) = h;
            psum[0] += h.x; psq[0] += h.x * h.x;
            psum[1] += h.y; psq[1] += h.y * h.y;
            psum[2] += h.z; psq[2] += h.z * h.z;
            psum[3] += h.w; psq[3] += h.w * h.w;
        }
    }
    #pragma unroll
    for (int off = 8; off >= 1; off >>= 1) {
        #pragma unroll
        for (int b = 0; b < 4; ++b) {
            psum[b] += __shfl_down(psum[b], off, 16);
            psq[b]  += __shfl_down(psq[b],  off, 16);
        }
    }
    if ((t & 15) == 0) {
        float* sp = stats8 + (size_t)(blockIdx.x & 7) * 128;
        #pragma unroll
        for (int b = 0; b < 4; ++b) {
            unsafeAtomicAdd(sp + j0 + b,      psum[b]);
            unsafeAtomicAdd(sp + 64 + j0 + b, psq[b]);
        }
    }
}

// ---------------------------------------------------------------------------
// K2.5: fold the 8 stat shards, produce scale/shift per column.
// ---------------------------------------------------------------------------
__global__ void bnstats_k(const float* __restrict__ stats8,
                          const float* __restrict__ gamma,
                          const float* __restrict__ beta,
                          float* __restrict__ sf)
{
    int j = threadIdx.x;  // 64 threads
    float s = 0.f, q = 0.f;
    #pragma unroll
    for (int c = 0; c < 8; ++c) {
        s += stats8[c * 128 + j];
        q += stats8[c * 128 + 64 + j];
    }
    const float invN = 1.0f / (float)N_NODES;
    float mean  = s * invN;
    float var   = q * invN - mean * mean;
    float scale = gamma[j] * rsqrtf(var + BN_EPS);
    sf[j]      = scale;
    sf[64 + j] = beta[j] - mean * scale;
}

// ---------------------------------------------------------------------------
// K3: out = relu(h2*scale + shift) + feat  (h2 lives in d_out, in-place)
// ---------------------------------------------------------------------------
__global__ __launch_bounds__(256) void finish_k(
    const float* __restrict__ feat, const float* __restrict__ sf,
    float* __restrict__ out)
{
    __shared__ float scs[64], shs[64];
    if (threadIdx.x < 64) {
        scs[threadIdx.x] = sf[threadIdx.x];
        shs[threadIdx.x] = sf[64 + threadIdx.x];
    }
    __syncthreads();
    size_t i = (size_t)blockIdx.x * 256 + threadIdx.x;   // float4 index
    if (i < (size_t)N_NODES * D / 4) {
        int j = (int)((i * 4) & 63);
        float4 h = *(float4*)(out + i * 4);
        float4 f = *(const float4*)(feat + i * 4);
        h.x = fmaxf(fmaf(h.x, scs[j + 0], shs[j + 0]), 0.f) + f.x;
        h.y = fmaxf(fmaf(h.y, scs[j + 1], shs[j + 1]), 0.f) + f.y;
        h.z = fmaxf(fmaf(h.z, scs[j + 2], shs[j + 2]), 0.f) + f.z;
        h.w = fmaxf(fmaf(h.w, scs[j + 3], shs[j + 3]), 0.f) + f.w;
        *(float4*)(out + i * 4) = h;
    }
}

extern "C" void kernel_launch(void* const* d_in, const int* in_sizes, int n_in,
                              void* d_out, int out_size, void* d_ws, size_t ws_size,
                              hipStream_t stream)
{
    const float* feat  = (const float*)d_in[0];
    const int*   src   = (const int*)d_in[1];
    const int*   dst   = (const int*)d_in[2];
    const float* eps   = (const float*)d_in[3];
    const float* W1    = (const float*)d_in[4];
    const float* b1    = (const float*)d_in[5];
    const float* W2    = (const float*)d_in[6];
    const float* b2    = (const float*)d_in[7];
    const float* gamma = (const float*)d_in[8];
    const float* beta  = (const float*)d_in[9];
    float* out = (float*)d_out;

    // workspace layout
    float* neigh  = (float*)d_ws;                         // N_NODES*64 floats
    int*   col    = (int*)(neigh + (size_t)N_NODES * D);  // N_EDGES ints
    int*   rowptr = col + N_EDGES;                        // N_NODES+1 ints
    int*   cursor = rowptr + (N_NODES + 1);               // N_NODES ints
    int*   deg    = cursor + N_NODES;                     // N_NODES ints
    float* stats8 = (float*)(deg + N_NODES);              // 8*128 floats
    float* sf     = stats8 + 1024;                        // 128 floats
    int*   bs     = (int*)(sf + 128);                     // NB ints
    int*   boff   = bs + NB;                              // NB ints

    // zero deg + stats8 (contiguous)
    hipMemsetAsync(deg, 0, (size_t)N_NODES * sizeof(int) + 1024 * sizeof(float), stream);

    hist_k<<<(N_EDGES + 255) / 256, 256, 0, stream>>>(dst, deg);
    blocksum_k<<<NB, 256, 0, stream>>>(deg, bs);
    scanblk_k<<<1, 512, 0, stream>>>(bs, boff);
    scan_out_k<<<NB, 256, 0, stream>>>(deg, boff, rowptr, cursor);
    fill_k<<<(N_EDGES + 255) / 256, 256, 0, stream>>>(src, dst, cursor, col);
    gather_k<<<(N_NODES + 3) / 4, 256, 0, stream>>>(feat, rowptr, col, neigh);
    mlp_k<<<(N_NODES + 63) / 64, 256, 0, stream>>>(feat, neigh, eps, W1, b1, W2, b2, out, stats8);
    bnstats_k<<<1, 64, 0, stream>>>(stats8, gamma, beta, sf);
    finish_k<<<(N_NODES * D / 4 + 255) / 256, 256, 0, stream>>>(feat, sf, out);
}

// Round 4
// 352.846 us; speedup vs baseline: 4.2587x; 1.1205x over previous
//
#include <hip/hip_runtime.h>

#define N_NODES 100000
#define N_EDGES 1600000
#define D 64
#define BN_EPS 1e-5f
#define NB ((N_NODES + 255) / 256)   // 391 scan blocks
#define NBKT 16
#define BKT_CAP 131072               // expected ~100K/bucket, binomial sigma ~310
#define NCHUNK 48                    // blocks per bucket in hist2/fill2

// ---------------------------------------------------------------------------
// Bucket pass: split edges into 16 dst-range buckets ((src,dst) int2 records).
// LDS histogram -> one global atomicAdd per bucket per block -> append.
// Bucket b covers dst in [6250*b, 6250*(b+1)) (deterministic per dst).
// ---------------------------------------------------------------------------
__global__ __launch_bounds__(256) void bucket_k(
    const int* __restrict__ src, const int* __restrict__ dst,
    int* __restrict__ bkt_cnt, int2* __restrict__ bktbuf)
{
    __shared__ int h[NBKT], base[NBKT], cur[NBKT];
    const int t = threadIdx.x;
    if (t < NBKT) { h[t] = 0; cur[t] = 0; }
    __syncthreads();
    const int e0 = blockIdx.x * 4096;
    int s[16], d[16], b[16];
    #pragma unroll
    for (int i = 0; i < 16; ++i) {
        int e = e0 + i * 256 + t;
        if (e < N_EDGES) {
            s[i] = src[e];
            d[i] = dst[e];
            b[i] = (int)((float)d[i] * (16.0f / 100000.0f));
            atomicAdd(&h[b[i]], 1);
        } else {
            b[i] = -1;
        }
    }
    __syncthreads();
    if (t < NBKT) base[t] = atomicAdd(&bkt_cnt[t], h[t]);
    __syncthreads();
    #pragma unroll
    for (int i = 0; i < 16; ++i) {
        if (b[i] >= 0) {
            int p = atomicAdd(&cur[b[i]], 1);
            bktbuf[(size_t)b[i] * BKT_CAP + base[b[i]] + p] = make_int2(s[i], d[i]);
        }
    }
}

// ---------------------------------------------------------------------------
// XCD-affine degree histogram from bucketed edges. deg pre-zeroed.
// bucket = blockIdx & 15 -> (heuristically) XCD b&7; deg region per bucket
// is ~25KB, L2-local.
// ---------------------------------------------------------------------------
__global__ __launch_bounds__(256) void hist2_k(
    const int2* __restrict__ bktbuf, const int* __restrict__ bkt_cnt,
    int* __restrict__ deg)
{
    const int b = blockIdx.x & (NBKT - 1);
    const int chunk = blockIdx.x >> 4;
    const int cnt = bkt_cnt[b];
    const int per = (cnt + NCHUNK - 1) / NCHUNK;
    int lo = chunk * per;
    int hi = min(lo + per, cnt);
    const int2* buf = bktbuf + (size_t)b * BKT_CAP;
    for (int i = lo + threadIdx.x; i < hi; i += 256)
        atomicAdd(&deg[buf[i].y], 1);
}

// ---------------------------------------------------------------------------
// Scan phase A: per-block (256-elem) sums of deg.
// ---------------------------------------------------------------------------
__global__ __launch_bounds__(256) void blocksum_k(
    const int* __restrict__ deg, int* __restrict__ bs)
{
    int i = blockIdx.x * 256 + threadIdx.x;
    int v = (i < N_NODES) ? deg[i] : 0;
    #pragma unroll
    for (int off = 32; off >= 1; off >>= 1) v += __shfl_down(v, off, 64);
    __shared__ int s[4];
    if ((threadIdx.x & 63) == 0) s[threadIdx.x >> 6] = v;
    __syncthreads();
    if (threadIdx.x == 0) bs[blockIdx.x] = s[0] + s[1] + s[2] + s[3];
}

// ---------------------------------------------------------------------------
// Scan phase B: one block scans the NB block sums -> exclusive offsets.
// ---------------------------------------------------------------------------
__global__ __launch_bounds__(512) void scanblk_k(
    const int* __restrict__ bs, int* __restrict__ boff)
{
    __shared__ int part[512];
    int t = threadIdx.x;
    int v = (t < NB) ? bs[t] : 0;
    part[t] = v;
    __syncthreads();
    for (int off = 1; off < 512; off <<= 1) {
        int x = part[t];
        int u = (t >= off) ? part[t - off] : 0;
        __syncthreads();
        part[t] = x + u;
        __syncthreads();
    }
    if (t < NBKT * 0 + 512 && t < NB) boff[t] = part[t] - v;   // exclusive
}

// ---------------------------------------------------------------------------
// Scan phase C: block-local exclusive scan + block offset -> rowptr/cursor.
// ---------------------------------------------------------------------------
__global__ __launch_bounds__(256) void scan_out_k(
    const int* __restrict__ deg, const int* __restrict__ boff,
    int* __restrict__ rowptr, int* __restrict__ cursor)
{
    int i = blockIdx.x * 256 + threadIdx.x;
    int v = (i < N_NODES) ? deg[i] : 0;
    int lane = threadIdx.x & 63;
    int w = threadIdx.x >> 6;
    int x = v;
    #pragma unroll
    for (int off = 1; off < 64; off <<= 1) {
        int u = __shfl_up(x, off, 64);
        if (lane >= off) x += u;
    }
    __shared__ int wsum[4];
    if (lane == 63) wsum[w] = x;
    __syncthreads();
    int woff = 0;
    #pragma unroll
    for (int j = 0; j < 4; ++j) woff += (j < w) ? wsum[j] : 0;
    int excl = boff[blockIdx.x] + woff + x - v;
    if (i < N_NODES) {
        rowptr[i] = excl;
        cursor[i] = excl;
        if (i == N_NODES - 1) rowptr[N_NODES] = excl + v;
    }
}

// ---------------------------------------------------------------------------
// XCD-affine CSR fill from bucketed edges. Bucket b's cursor (~25KB) and col
// (~400KB) regions stay hot in one XCD's L2 -> full-line writebacks.
// ---------------------------------------------------------------------------
__global__ __launch_bounds__(256) void fill2_k(
    const int2* __restrict__ bktbuf, const int* __restrict__ bkt_cnt,
    int* __restrict__ cursor, int* __restrict__ col)
{
    const int b = blockIdx.x & (NBKT - 1);
    const int chunk = blockIdx.x >> 4;
    const int cnt = bkt_cnt[b];
    const int per = (cnt + NCHUNK - 1) / NCHUNK;
    int lo = chunk * per;
    int hi = min(lo + per, cnt);
    const int2* buf = bktbuf + (size_t)b * BKT_CAP;
    for (int i = lo + threadIdx.x; i < hi; i += 256) {
        int2 r = buf[i];
        int slot = atomicAdd(&cursor[r.y], 1);
        col[slot] = r.x;
    }
}

// ---------------------------------------------------------------------------
// K1: gather-sum. One wave per node. Lanes form 4 groups of 16; group g
// handles edges lo+g, lo+g+4, ... Each lane loads float4 (16B) -> one edge
// row = 16 lanes x 16B = 256B coalesced. Final 2-step shfl_xor merges groups.
// ---------------------------------------------------------------------------
__global__ __launch_bounds__(256) void gather_k(
    const float* __restrict__ feat, const int* __restrict__ rowptr,
    const int* __restrict__ col, float* __restrict__ neigh)
{
    int node = blockIdx.x * 4 + (threadIdx.x >> 6);
    int lane = threadIdx.x & 63;
    if (node >= N_NODES) return;
    int g = lane >> 4;            // edge group 0..3
    int c = (lane & 15) << 2;     // column base
    int lo = rowptr[node];
    int hi = rowptr[node + 1];
    float ax = 0.f, ay = 0.f, az = 0.f, aw = 0.f;
    int e = lo + g;
    for (; e + 4 < hi; e += 8) {
        int s0 = col[e];
        int s1 = col[e + 4];
        float4 v0 = *(const float4*)(feat + (size_t)s0 * D + c);
        float4 v1 = *(const float4*)(feat + (size_t)s1 * D + c);
        ax += v0.x; ay += v0.y; az += v0.z; aw += v0.w;
        ax += v1.x; ay += v1.y; az += v1.z; aw += v1.w;
    }
    if (e < hi) {
        float4 v = *(const float4*)(feat + (size_t)col[e] * D + c);
        ax += v.x; ay += v.y; az += v.z; aw += v.w;
    }
    #pragma unroll
    for (int off = 16; off <= 32; off <<= 1) {
        ax += __shfl_xor(ax, off, 64);
        ay += __shfl_xor(ay, off, 64);
        az += __shfl_xor(az, off, 64);
        aw += __shfl_xor(aw, off, 64);
    }
    if (g == 0) {
        float4 r; r.x = ax; r.y = ay; r.z = az; r.w = aw;
        *(float4*)(neigh + (size_t)node * D + c) = r;
    }
}

// ---------------------------------------------------------------------------
// K2: per 64-node tile: x = (1+eps)*feat + neigh; h2 = relu(x@W1+b1)@W2+b2.
// Writes h2 to d_out (temp), accumulates BN partials into stats8.
// ---------------------------------------------------------------------------
__global__ __launch_bounds__(256) void mlp_k(
    const float* __restrict__ feat, const float* __restrict__ neigh,
    const float* __restrict__ epsp,
    const float* __restrict__ W1, const float* __restrict__ b1,
    const float* __restrict__ W2, const float* __restrict__ b2,
    float* __restrict__ h2out, float* __restrict__ stats8)
{
    __shared__ float W1s[64 * 68];
    __shared__ float W2s[64 * 68];
    __shared__ float xs[64 * 65];
    __shared__ float b1s[64], b2s[64];

    const int t  = threadIdx.x;
    const int nb = blockIdx.x * 64;

    #pragma unroll
    for (int i = 0; i < 4; ++i) {
        int l  = t + i * 256;
        int k  = l >> 4;
        int j4 = (l & 15) << 2;
        float4 w1 = *(const float4*)(W1 + k * 64 + j4);
        float4 w2 = *(const float4*)(W2 + k * 64 + j4);
        *(float4*)(&W1s[k * 68 + j4]) = w1;
        *(float4*)(&W2s[k * 68 + j4]) = w2;
    }
    if (t < 64)       b1s[t]      = b1[t];
    else if (t < 128) b2s[t - 64] = b2[t - 64];

    const float epsv = 1.0f + epsp[0];

    #pragma unroll
    for (int i = 0; i < 4; ++i) {
        int n  = (t >> 4) + i * 16;
        int k4 = (t & 15) << 2;
        int gn = nb + n;
        float4 f = make_float4(0.f, 0.f, 0.f, 0.f);
        float4 g = make_float4(0.f, 0.f, 0.f, 0.f);
        if (gn < N_NODES) {
            f = *(const float4*)(feat  + (size_t)gn * 64 + k4);
            g = *(const float4*)(neigh + (size_t)gn * 64 + k4);
        }
        xs[n * 65 + k4 + 0] = epsv * f.x + g.x;
        xs[n * 65 + k4 + 1] = epsv * f.y + g.y;
        xs[n * 65 + k4 + 2] = epsv * f.z + g.z;
        xs[n * 65 + k4 + 3] = epsv * f.w + g.w;
    }
    __syncthreads();

    const int n0 = (t & 15) << 2;
    const int j0 = (t >> 4) << 2;

    const float* xr0 = &xs[(n0 + 0) * 65];
    const float* xr1 = &xs[(n0 + 1) * 65];
    const float* xr2 = &xs[(n0 + 2) * 65];
    const float* xr3 = &xs[(n0 + 3) * 65];

    float acc[4][4];
    #pragma unroll
    for (int a = 0; a < 4; ++a)
        #pragma unroll
        for (int b = 0; b < 4; ++b)
            acc[a][b] = b1s[j0 + b];

    #pragma unroll 8
    for (int k = 0; k < 64; ++k) {
        const float4 w = *(const float4*)(&W1s[k * 68 + j0]);
        const float x0 = xr0[k], x1 = xr1[k], x2 = xr2[k], x3 = xr3[k];
        acc[0][0] = fmaf(x0, w.x, acc[0][0]);
        acc[0][1] = fmaf(x0, w.y, acc[0][1]);
        acc[0][2] = fmaf(x0, w.z, acc[0][2]);
        acc[0][3] = fmaf(x0, w.w, acc[0][3]);
        acc[1][0] = fmaf(x1, w.x, acc[1][0]);
        acc[1][1] = fmaf(x1, w.y, acc[1][1]);
        acc[1][2] = fmaf(x1, w.z, acc[1][2]);
        acc[1][3] = fmaf(x1, w.w, acc[1][3]);
        acc[2][0] = fmaf(x2, w.x, acc[2][0]);
        acc[2][1] = fmaf(x2, w.y, acc[2][1]);
        acc[2][2] = fmaf(x2, w.z, acc[2][2]);
        acc[2][3] = fmaf(x2, w.w, acc[2][3]);
        acc[3][0] = fmaf(x3, w.x, acc[3][0]);
        acc[3][1] = fmaf(x3, w.y, acc[3][1]);
        acc[3][2] = fmaf(x3, w.z, acc[3][2]);
        acc[3][3] = fmaf(x3, w.w, acc[3][3]);
    }

    __syncthreads();
    #pragma unroll
    for (int a = 0; a < 4; ++a)
        #pragma unroll
        for (int b = 0; b < 4; ++b)
            xs[(n0 + a) * 65 + j0 + b] = fmaxf(acc[a][b], 0.0f);
    __syncthreads();

    float acc2[4][4];
    #pragma unroll
    for (int a = 0; a < 4; ++a)
        #pragma unroll
        for (int b = 0; b < 4; ++b)
            acc2[a][b] = b2s[j0 + b];

    #pragma unroll 8
    for (int k = 0; k < 64; ++k) {
        const float4 w = *(const float4*)(&W2s[k * 68 + j0]);
        const float x0 = xr0[k], x1 = xr1[k], x2 = xr2[k], x3 = xr3[k];
        acc2[0][0] = fmaf(x0, w.x, acc2[0][0]);
        acc2[0][1] = fmaf(x0, w.y, acc2[0][1]);
        acc2[0][2] = fmaf(x0, w.z, acc2[0][2]);
        acc2[0][3] = fmaf(x0, w.w, acc2[0][3]);
        acc2[1][0] = fmaf(x1, w.x, acc2[1][0]);
        acc2[1][1] = fmaf(x1, w.y, acc2[1][1]);
        acc2[1][2] = fmaf(x1, w.z, acc2[1][2]);
        acc2[1][3] = fmaf(x1, w.w, acc2[1][3]);
        acc2[2][0] = fmaf(x2, w.x, acc2[2][0]);
        acc2[2][1] = fmaf(x2, w.y, acc2[2][1]);
        acc2[2][2] = fmaf(x2, w.z, acc2[2][2]);
        acc2[2][3] = fmaf(x2, w.w, acc2[2][3]);
        acc2[3][0] = fmaf(x3, w.x, acc2[3][0]);
        acc2[3][1] = fmaf(x3, w.y, acc2[3][1]);
        acc2[3][2] = fmaf(x3, w.z, acc2[3][2]);
        acc2[3][3] = fmaf(x3, w.w, acc2[3][3]);
    }

    float psum[4] = {0.f, 0.f, 0.f, 0.f};
    float psq[4]  = {0.f, 0.f, 0.f, 0.f};
    #pragma unroll
    for (int a = 0; a < 4; ++a) {
        int gn = nb + n0 + a;
        if (gn < N_NODES) {
            float4 h;
            h.x = acc2[a][0]; h.y = acc2[a][1]; h.z = acc2[a][2]; h.w = acc2[a][3];
            *(float4*)(h2out + (size_t)gn * 64 + j0) = h;
            psum[0] += h.x; psq[0] += h.x * h.x;
            psum[1] += h.y; psq[1] += h.y * h.y;
            psum[2] += h.z; psq[2] += h.z * h.z;
            psum[3] += h.w; psq[3] += h.w * h.w;
        }
    }
    #pragma unroll
    for (int off = 8; off >= 1; off >>= 1) {
        #pragma unroll
        for (int b = 0; b < 4; ++b) {
            psum[b] += __shfl_down(psum[b], off, 16);
            psq[b]  += __shfl_down(psq[b],  off, 16);
        }
    }
    if ((t & 15) == 0) {
        float* sp = stats8 + (size_t)(blockIdx.x & 7) * 128;
        #pragma unroll
        for (int b = 0; b < 4; ++b) {
            unsafeAtomicAdd(sp + j0 + b,      psum[b]);
            unsafeAtomicAdd(sp + 64 + j0 + b, psq[b]);
        }
    }
}

// ---------------------------------------------------------------------------
// K2.5: fold the 8 stat shards, produce scale/shift per column.
// ---------------------------------------------------------------------------
__global__ void bnstats_k(const float* __restrict__ stats8,
                          const float* __restrict__ gamma,
                          const float* __restrict__ beta,
                          float* __restrict__ sf)
{
    int j = threadIdx.x;  // 64 threads
    float s = 0.f, q = 0.f;
    #pragma unroll
    for (int c = 0; c < 8; ++c) {
        s += stats8[c * 128 + j];
        q += stats8[c * 128 + 64 + j];
    }
    const float invN = 1.0f / (float)N_NODES;
    float mean  = s * invN;
    float var   = q * invN - mean * mean;
    float scale = gamma[j] * rsqrtf(var + BN_EPS);
    sf[j]      = scale;
    sf[64 + j] = beta[j] - mean * scale;
}

// ---------------------------------------------------------------------------
// K3: out = relu(h2*scale + shift) + feat  (h2 lives in d_out, in-place)
// ---------------------------------------------------------------------------
__global__ __launch_bounds__(256) void finish_k(
    const float* __restrict__ feat, const float* __restrict__ sf,
    float* __restrict__ out)
{
    __shared__ float scs[64], shs[64];
    if (threadIdx.x < 64) {
        scs[threadIdx.x] = sf[threadIdx.x];
        shs[threadIdx.x] = sf[64 + threadIdx.x];
    }
    __syncthreads();
    size_t i = (size_t)blockIdx.x * 256 + threadIdx.x;   // float4 index
    if (i < (size_t)N_NODES * D / 4) {
        int j = (int)((i * 4) & 63);
        float4 h = *(float4*)(out + i * 4);
        float4 f = *(const float4*)(feat + i * 4);
        h.x = fmaxf(fmaf(h.x, scs[j + 0], shs[j + 0]), 0.f) + f.x;
        h.y = fmaxf(fmaf(h.y, scs[j + 1], shs[j + 1]), 0.f) + f.y;
        h.z = fmaxf(fmaf(h.z, scs[j + 2], shs[j + 2]), 0.f) + f.z;
        h.w = fmaxf(fmaf(h.w, scs[j + 3], shs[j + 3]), 0.f) + f.w;
        *(float4*)(out + i * 4) = h;
    }
}

extern "C" void kernel_launch(void* const* d_in, const int* in_sizes, int n_in,
                              void* d_out, int out_size, void* d_ws, size_t ws_size,
                              hipStream_t stream)
{
    const float* feat  = (const float*)d_in[0];
    const int*   src   = (const int*)d_in[1];
    const int*   dst   = (const int*)d_in[2];
    const float* eps   = (const float*)d_in[3];
    const float* W1    = (const float*)d_in[4];
    const float* b1    = (const float*)d_in[5];
    const float* W2    = (const float*)d_in[6];
    const float* b2    = (const float*)d_in[7];
    const float* gamma = (const float*)d_in[8];
    const float* beta  = (const float*)d_in[9];
    float* out = (float*)d_out;

    // workspace layout. bktbuf (16 MB) aliases neigh (25.6 MB): bucket/fill
    // phases finish before gather_k writes every neigh row.
    float* neigh   = (float*)d_ws;                         // N_NODES*64 floats
    int2*  bktbuf  = (int2*)d_ws;                          // NBKT*BKT_CAP int2
    int*   col     = (int*)(neigh + (size_t)N_NODES * D);  // N_EDGES ints
    int*   rowptr  = col + N_EDGES;                        // N_NODES+1 ints
    int*   cursor  = rowptr + (N_NODES + 1);               // N_NODES ints
    int*   deg     = cursor + N_NODES;                     // N_NODES ints
    float* stats8  = (float*)(deg + N_NODES);              // 8*128 floats
    int*   bkt_cnt = (int*)(stats8 + 1024);                // NBKT ints
    float* sf      = (float*)(bkt_cnt + NBKT);             // 128 floats
    int*   bs      = (int*)(sf + 128);                     // NB ints
    int*   boff    = bs + NB;                              // NB ints

    // zero deg + stats8 + bkt_cnt (contiguous)
    hipMemsetAsync(deg, 0,
                   (size_t)N_NODES * sizeof(int) + 1024 * sizeof(float) + NBKT * sizeof(int),
                   stream);

    bucket_k<<<(N_EDGES + 4095) / 4096, 256, 0, stream>>>(src, dst, bkt_cnt, bktbuf);
    hist2_k<<<NBKT * NCHUNK, 256, 0, stream>>>(bktbuf, bkt_cnt, deg);
    blocksum_k<<<NB, 256, 0, stream>>>(deg, bs);
    scanblk_k<<<1, 512, 0, stream>>>(bs, boff);
    scan_out_k<<<NB, 256, 0, stream>>>(deg, boff, rowptr, cursor);
    fill2_k<<<NBKT * NCHUNK, 256, 0, stream>>>(bktbuf, bkt_cnt, cursor, col);
    gather_k<<<(N_NODES + 3) / 4, 256, 0, stream>>>(feat, rowptr, col, neigh);
    mlp_k<<<(N_NODES + 63) / 64, 256, 0, stream>>>(feat, neigh, eps, W1, b1, W2, b2, out, stats8);
    bnstats_k<<<1, 64, 0, stream>>>(stats8, gamma, beta, sf);
    finish_k<<<(N_NODES * D / 4 + 255) / 256, 256, 0, stream>>>(feat, sf, out);
}

// Round 5
// 255.923 us; speedup vs baseline: 5.8716x; 1.3787x over previous
//
#include <hip/hip_runtime.h>

#define N_NODES 100000
#define N_EDGES 1600000
#define D 64
#define BN_EPS 1e-5f
#define NBKT 64
#define NPB 1563                 // nodes per bucket: 64*1563 = 100032 >= 100000
#define BKT_CAP 32768            // expected ~25008/bucket, sigma ~157
#define SORT_T 1024              // threads in sort_k

// ---------------------------------------------------------------------------
// Bucket pass: split edges into 64 dst-range buckets ((src,dst) int2 records).
// Bucket b covers dst in [1563*b, 1563*(b+1)).
// ---------------------------------------------------------------------------
__global__ __launch_bounds__(256) void bucket_k(
    const int* __restrict__ src, const int* __restrict__ dst,
    int* __restrict__ bkt_cnt, int2* __restrict__ bktbuf)
{
    __shared__ int h[NBKT], base[NBKT], cur[NBKT];
    const int t = threadIdx.x;
    if (t < NBKT) { h[t] = 0; cur[t] = 0; }
    __syncthreads();
    const int e0 = blockIdx.x * 4096;
    int s[16], d[16], b[16];
    #pragma unroll
    for (int i = 0; i < 16; ++i) {
        int e = e0 + i * 256 + t;
        if (e < N_EDGES) {
            s[i] = src[e];
            d[i] = dst[e];
            b[i] = d[i] / NPB;
            atomicAdd(&h[b[i]], 1);
        } else {
            b[i] = -1;
        }
    }
    __syncthreads();
    if (t < NBKT) base[t] = atomicAdd(&bkt_cnt[t], h[t]);
    __syncthreads();
    #pragma unroll
    for (int i = 0; i < 16; ++i) {
        if (b[i] >= 0) {
            int p = atomicAdd(&cur[b[i]], 1);
            bktbuf[(size_t)b[i] * BKT_CAP + base[b[i]] + p] = make_int2(s[i], d[i]);
        }
    }
}

// ---------------------------------------------------------------------------
// sort_k: one block per bucket. LDS counting sort over the bucket's 1563
// nodes: histogram (LDS atomics) -> block scan -> coalesced rowptr segment
// write -> CSR fill via LDS cursor atomics. col writes stay within one
// ~100KB region touched by ONE CU -> one XCD L2 -> full-line writebacks.
// Replaces hist2/blocksum/scanblk/scan_out/fill2 and all global cursor
// atomics of the previous version.
// ---------------------------------------------------------------------------
__global__ __launch_bounds__(SORT_T) void sort_k(
    const int2* __restrict__ bktbuf, const int* __restrict__ bkt_cnt,
    int* __restrict__ rowptr, int* __restrict__ col)
{
    __shared__ int h[NPB];
    __shared__ int cur[NPB];
    __shared__ int part[SORT_T];
    __shared__ int gbase_s;

    const int b = blockIdx.x;
    const int t = threadIdx.x;
    const int nb0 = b * NPB;
    const int nodes_in = min(NPB, N_NODES - nb0);
    const int cnt = bkt_cnt[b];
    const int2* buf = bktbuf + (size_t)b * BKT_CAP;

    // exclusive scan of bkt_cnt over 64 buckets (wave 0) -> global col base
    if (t < 64) {
        int v = bkt_cnt[t];
        int x = v;
        #pragma unroll
        for (int off = 1; off < 64; off <<= 1) {
            int u = __shfl_up(x, off, 64);
            if (t >= off) x += u;
        }
        if (t == b) gbase_s = x - v;   // exclusive prefix at b  (b < 64)
    }
    // zero histogram
    for (int j = t; j < NPB; j += SORT_T) h[j] = 0;
    __syncthreads();
    const int gbase = gbase_s;

    // pass 1: degree histogram (LDS atomics)
    for (int i = t; i < cnt; i += SORT_T)
        atomicAdd(&h[buf[i].y - nb0], 1);
    __syncthreads();

    // block exclusive scan over NPB entries: 2 elements per thread
    int e0 = 2 * t, e1 = 2 * t + 1;
    int a  = (e0 < NPB) ? h[e0] : 0;
    int b_ = (e1 < NPB) ? h[e1] : 0;
    part[t] = a + b_;
    __syncthreads();
    for (int off = 1; off < SORT_T; off <<= 1) {
        int x = part[t];
        int u = (t >= off) ? part[t - off] : 0;
        __syncthreads();
        part[t] = x + u;
        __syncthreads();
    }
    int excl = part[t] - (a + b_);   // exclusive prefix at e0
    if (e0 < NPB) {
        cur[e0] = excl;
        if (e0 < nodes_in) rowptr[nb0 + e0] = gbase + excl;
    }
    if (e1 < NPB) {
        cur[e1] = excl + a;
        if (e1 < nodes_in) rowptr[nb0 + e1] = gbase + excl + a;
    }
    if (b == NBKT - 1 && t == 0) rowptr[N_NODES] = gbase + cnt;  // == N_EDGES
    __syncthreads();

    // pass 2: place edges (LDS cursor atomics, one-XCD col writes)
    for (int i = t; i < cnt; i += SORT_T) {
        int2 r = buf[i];
        int slot = atomicAdd(&cur[r.y - nb0], 1);
        col[gbase + slot] = r.x;
    }
}

// ---------------------------------------------------------------------------
// K1: gather-sum. One wave per node. Lanes form 4 groups of 16; group g
// handles edges lo+g, lo+g+4, ... Each lane loads float4 (16B) -> one edge
// row = 16 lanes x 16B = 256B coalesced. Final 2-step shfl_xor merges groups.
// ---------------------------------------------------------------------------
__global__ __launch_bounds__(256) void gather_k(
    const float* __restrict__ feat, const int* __restrict__ rowptr,
    const int* __restrict__ col, float* __restrict__ neigh)
{
    int node = blockIdx.x * 4 + (threadIdx.x >> 6);
    int lane = threadIdx.x & 63;
    if (node >= N_NODES) return;
    int g = lane >> 4;            // edge group 0..3
    int c = (lane & 15) << 2;     // column base
    int lo = rowptr[node];
    int hi = rowptr[node + 1];
    float ax = 0.f, ay = 0.f, az = 0.f, aw = 0.f;
    int e = lo + g;
    for (; e + 4 < hi; e += 8) {
        int s0 = col[e];
        int s1 = col[e + 4];
        float4 v0 = *(const float4*)(feat + (size_t)s0 * D + c);
        float4 v1 = *(const float4*)(feat + (size_t)s1 * D + c);
        ax += v0.x; ay += v0.y; az += v0.z; aw += v0.w;
        ax += v1.x; ay += v1.y; az += v1.z; aw += v1.w;
    }
    if (e < hi) {
        float4 v = *(const float4*)(feat + (size_t)col[e] * D + c);
        ax += v.x; ay += v.y; az += v.z; aw += v.w;
    }
    #pragma unroll
    for (int off = 16; off <= 32; off <<= 1) {
        ax += __shfl_xor(ax, off, 64);
        ay += __shfl_xor(ay, off, 64);
        az += __shfl_xor(az, off, 64);
        aw += __shfl_xor(aw, off, 64);
    }
    if (g == 0) {
        float4 r; r.x = ax; r.y = ay; r.z = az; r.w = aw;
        *(float4*)(neigh + (size_t)node * D + c) = r;
    }
}

// ---------------------------------------------------------------------------
// K2: per 64-node tile: x = (1+eps)*feat + neigh; h2 = relu(x@W1+b1)@W2+b2.
// Writes h2 to d_out (temp), accumulates BN partials into stats8.
// ---------------------------------------------------------------------------
__global__ __launch_bounds__(256) void mlp_k(
    const float* __restrict__ feat, const float* __restrict__ neigh,
    const float* __restrict__ epsp,
    const float* __restrict__ W1, const float* __restrict__ b1,
    const float* __restrict__ W2, const float* __restrict__ b2,
    float* __restrict__ h2out, float* __restrict__ stats8)
{
    __shared__ float W1s[64 * 68];
    __shared__ float W2s[64 * 68];
    __shared__ float xs[64 * 65];
    __shared__ float b1s[64], b2s[64];

    const int t  = threadIdx.x;
    const int nb = blockIdx.x * 64;

    #pragma unroll
    for (int i = 0; i < 4; ++i) {
        int l  = t + i * 256;
        int k  = l >> 4;
        int j4 = (l & 15) << 2;
        float4 w1 = *(const float4*)(W1 + k * 64 + j4);
        float4 w2 = *(const float4*)(W2 + k * 64 + j4);
        *(float4*)(&W1s[k * 68 + j4]) = w1;
        *(float4*)(&W2s[k * 68 + j4]) = w2;
    }
    if (t < 64)       b1s[t]      = b1[t];
    else if (t < 128) b2s[t - 64] = b2[t - 64];

    const float epsv = 1.0f + epsp[0];

    #pragma unroll
    for (int i = 0; i < 4; ++i) {
        int n  = (t >> 4) + i * 16;
        int k4 = (t & 15) << 2;
        int gn = nb + n;
        float4 f = make_float4(0.f, 0.f, 0.f, 0.f);
        float4 g = make_float4(0.f, 0.f, 0.f, 0.f);
        if (gn < N_NODES) {
            f = *(const float4*)(feat  + (size_t)gn * 64 + k4);
            g = *(const float4*)(neigh + (size_t)gn * 64 + k4);
        }
        xs[n * 65 + k4 + 0] = epsv * f.x + g.x;
        xs[n * 65 + k4 + 1] = epsv * f.y + g.y;
        xs[n * 65 + k4 + 2] = epsv * f.z + g.z;
        xs[n * 65 + k4 + 3] = epsv * f.w + g.w;
    }
    __syncthreads();

    const int n0 = (t & 15) << 2;
    const int j0 = (t >> 4) << 2;

    const float* xr0 = &xs[(n0 + 0) * 65];
    const float* xr1 = &xs[(n0 + 1) * 65];
    const float* xr2 = &xs[(n0 + 2) * 65];
    const float* xr3 = &xs[(n0 + 3) * 65];

    float acc[4][4];
    #pragma unroll
    for (int a = 0; a < 4; ++a)
        #pragma unroll
        for (int b = 0; b < 4; ++b)
            acc[a][b] = b1s[j0 + b];

    #pragma unroll 8
    for (int k = 0; k < 64; ++k) {
        const float4 w = *(const float4*)(&W1s[k * 68 + j0]);
        const float x0 = xr0[k], x1 = xr1[k], x2 = xr2[k], x3 = xr3[k];
        acc[0][0] = fmaf(x0, w.x, acc[0][0]);
        acc[0][1] = fmaf(x0, w.y, acc[0][1]);
        acc[0][2] = fmaf(x0, w.z, acc[0][2]);
        acc[0][3] = fmaf(x0, w.w, acc[0][3]);
        acc[1][0] = fmaf(x1, w.x, acc[1][0]);
        acc[1][1] = fmaf(x1, w.y, acc[1][1]);
        acc[1][2] = fmaf(x1, w.z, acc[1][2]);
        acc[1][3] = fmaf(x1, w.w, acc[1][3]);
        acc[2][0] = fmaf(x2, w.x, acc[2][0]);
        acc[2][1] = fmaf(x2, w.y, acc[2][1]);
        acc[2][2] = fmaf(x2, w.z, acc[2][2]);
        acc[2][3] = fmaf(x2, w.w, acc[2][3]);
        acc[3][0] = fmaf(x3, w.x, acc[3][0]);
        acc[3][1] = fmaf(x3, w.y, acc[3][1]);
        acc[3][2] = fmaf(x3, w.z, acc[3][2]);
        acc[3][3] = fmaf(x3, w.w, acc[3][3]);
    }

    __syncthreads();
    #pragma unroll
    for (int a = 0; a < 4; ++a)
        #pragma unroll
        for (int b = 0; b < 4; ++b)
            xs[(n0 + a) * 65 + j0 + b] = fmaxf(acc[a][b], 0.0f);
    __syncthreads();

    float acc2[4][4];
    #pragma unroll
    for (int a = 0; a < 4; ++a)
        #pragma unroll
        for (int b = 0; b < 4; ++b)
            acc2[a][b] = b2s[j0 + b];

    #pragma unroll 8
    for (int k = 0; k < 64; ++k) {
        const float4 w = *(const float4*)(&W2s[k * 68 + j0]);
        const float x0 = xr0[k], x1 = xr1[k], x2 = xr2[k], x3 = xr3[k];
        acc2[0][0] = fmaf(x0, w.x, acc2[0][0]);
        acc2[0][1] = fmaf(x0, w.y, acc2[0][1]);
        acc2[0][2] = fmaf(x0, w.z, acc2[0][2]);
        acc2[0][3] = fmaf(x0, w.w, acc2[0][3]);
        acc2[1][0] = fmaf(x1, w.x, acc2[1][0]);
        acc2[1][1] = fmaf(x1, w.y, acc2[1][1]);
        acc2[1][2] = fmaf(x1, w.z, acc2[1][2]);
        acc2[1][3] = fmaf(x1, w.w, acc2[1][3]);
        acc2[2][0] = fmaf(x2, w.x, acc2[2][0]);
        acc2[2][1] = fmaf(x2, w.y, acc2[2][1]);
        acc2[2][2] = fmaf(x2, w.z, acc2[2][2]);
        acc2[2][3] = fmaf(x2, w.w, acc2[2][3]);
        acc2[3][0] = fmaf(x3, w.x, acc2[3][0]);
        acc2[3][1] = fmaf(x3, w.y, acc2[3][1]);
        acc2[3][2] = fmaf(x3, w.z, acc2[3][2]);
        acc2[3][3] = fmaf(x3, w.w, acc2[3][3]);
    }

    float psum[4] = {0.f, 0.f, 0.f, 0.f};
    float psq[4]  = {0.f, 0.f, 0.f, 0.f};
    #pragma unroll
    for (int a = 0; a < 4; ++a) {
        int gn = nb + n0 + a;
        if (gn < N_NODES) {
            float4 h;
            h.x = acc2[a][0]; h.y = acc2[a][1]; h.z = acc2[a][2]; h.w = acc2[a][3];
            *(float4*)(h2out + (size_t)gn * 64 + j0) = h;
            psum[0] += h.x; psq[0] += h.x * h.x;
            psum[1] += h.y; psq[1] += h.y * h.y;
            psum[2] += h.z; psq[2] += h.z * h.z;
            psum[3] += h.w; psq[3] += h.w * h.w;
        }
    }
    #pragma unroll
    for (int off = 8; off >= 1; off >>= 1) {
        #pragma unroll
        for (int b = 0; b < 4; ++b) {
            psum[b] += __shfl_down(psum[b], off, 16);
            psq[b]  += __shfl_down(psq[b],  off, 16);
        }
    }
    if ((t & 15) == 0) {
        float* sp = stats8 + (size_t)(blockIdx.x & 7) * 128;
        #pragma unroll
        for (int b = 0; b < 4; ++b) {
            unsafeAtomicAdd(sp + j0 + b,      psum[b]);
            unsafeAtomicAdd(sp + 64 + j0 + b, psq[b]);
        }
    }
}

// ---------------------------------------------------------------------------
// K2.5: fold the 8 stat shards, produce scale/shift per column.
// ---------------------------------------------------------------------------
__global__ void bnstats_k(const float* __restrict__ stats8,
                          const float* __restrict__ gamma,
                          const float* __restrict__ beta,
                          float* __restrict__ sf)
{
    int j = threadIdx.x;  // 64 threads
    float s = 0.f, q = 0.f;
    #pragma unroll
    for (int c = 0; c < 8; ++c) {
        s += stats8[c * 128 + j];
        q += stats8[c * 128 + 64 + j];
    }
    const float invN = 1.0f / (float)N_NODES;
    float mean  = s * invN;
    float var   = q * invN - mean * mean;
    float scale = gamma[j] * rsqrtf(var + BN_EPS);
    sf[j]      = scale;
    sf[64 + j] = beta[j] - mean * scale;
}

// ---------------------------------------------------------------------------
// K3: out = relu(h2*scale + shift) + feat  (h2 lives in d_out, in-place)
// ---------------------------------------------------------------------------
__global__ __launch_bounds__(256) void finish_k(
    const float* __restrict__ feat, const float* __restrict__ sf,
    float* __restrict__ out)
{
    __shared__ float scs[64], shs[64];
    if (threadIdx.x < 64) {
        scs[threadIdx.x] = sf[threadIdx.x];
        shs[threadIdx.x] = sf[64 + threadIdx.x];
    }
    __syncthreads();
    size_t i = (size_t)blockIdx.x * 256 + threadIdx.x;   // float4 index
    if (i < (size_t)N_NODES * D / 4) {
        int j = (int)((i * 4) & 63);
        float4 h = *(float4*)(out + i * 4);
        float4 f = *(const float4*)(feat + i * 4);
        h.x = fmaxf(fmaf(h.x, scs[j + 0], shs[j + 0]), 0.f) + f.x;
        h.y = fmaxf(fmaf(h.y, scs[j + 1], shs[j + 1]), 0.f) + f.y;
        h.z = fmaxf(fmaf(h.z, scs[j + 2], shs[j + 2]), 0.f) + f.z;
        h.w = fmaxf(fmaf(h.w, scs[j + 3], shs[j + 3]), 0.f) + f.w;
        *(float4*)(out + i * 4) = h;
    }
}

extern "C" void kernel_launch(void* const* d_in, const int* in_sizes, int n_in,
                              void* d_out, int out_size, void* d_ws, size_t ws_size,
                              hipStream_t stream)
{
    const float* feat  = (const float*)d_in[0];
    const int*   src   = (const int*)d_in[1];
    const int*   dst   = (const int*)d_in[2];
    const float* eps   = (const float*)d_in[3];
    const float* W1    = (const float*)d_in[4];
    const float* b1    = (const float*)d_in[5];
    const float* W2    = (const float*)d_in[6];
    const float* b2    = (const float*)d_in[7];
    const float* gamma = (const float*)d_in[8];
    const float* beta  = (const float*)d_in[9];
    float* out = (float*)d_out;

    // workspace layout. bktbuf (64*32768*8B = 16.8 MB) aliases neigh
    // (25.6 MB): bucket/sort finish before gather_k writes every neigh row.
    float* neigh   = (float*)d_ws;                         // N_NODES*64 floats
    int2*  bktbuf  = (int2*)d_ws;                          // NBKT*BKT_CAP int2
    int*   col     = (int*)(neigh + (size_t)N_NODES * D);  // N_EDGES ints
    int*   rowptr  = col + N_EDGES;                        // N_NODES+1 ints
    float* stats8  = (float*)(rowptr + N_NODES + 1);       // 8*128 floats
    int*   bkt_cnt = (int*)(stats8 + 1024);                // NBKT ints
    float* sf      = (float*)(bkt_cnt + NBKT);             // 128 floats

    // zero stats8 + bkt_cnt (contiguous, 4.3 KB)
    hipMemsetAsync(stats8, 0, 1024 * sizeof(float) + NBKT * sizeof(int), stream);

    bucket_k<<<(N_EDGES + 4095) / 4096, 256, 0, stream>>>(src, dst, bkt_cnt, bktbuf);
    sort_k<<<NBKT, SORT_T, 0, stream>>>(bktbuf, bkt_cnt, rowptr, col);
    gather_k<<<(N_NODES + 3) / 4, 256, 0, stream>>>(feat, rowptr, col, neigh);
    mlp_k<<<(N_NODES + 63) / 64, 256, 0, stream>>>(feat, neigh, eps, W1, b1, W2, b2, out, stats8);
    bnstats_k<<<1, 64, 0, stream>>>(stats8, gamma, beta, sf);
    finish_k<<<(N_NODES * D / 4 + 255) / 256, 256, 0, stream>>>(feat, sf, out);
}